// Round 2
// baseline (327.219 us; speedup 1.0000x reference)
//
#include <hip/hip_runtime.h>

constexpr int N_DST1 = 50000;
constexpr int N_DST2 = 10000;
constexpr int E1     = 2000000;
constexpr int E2     = 400000;
constexpr int IN_F   = 128;
constexpr int H_F    = 256;
constexpr int N_CLS  = 47;

// Workspace layout (bytes)
constexpr size_t RP1_OFF = 0;          // 50001 int
constexpr size_t RP2_OFF = 204800;     // 10001 int
constexpr size_t BPS_OFF = 245760;     // Ws1 packed bf16 frags: 64 KB
constexpr size_t BPN_OFF = 311296;     // Wn1 packed: 64 KB
constexpr size_t BP2_OFF = 376832;     // [Ws2;Wn2] packed: 48 KB
constexpr size_t X8_OFF  = 430080;     // x fp8: 200000*128 = 25.6 MB
constexpr size_t HB_OFF  = 38830080;   // h bf16 (rows < N_DST2 used)
constexpr size_t H8_OFF  = 64430080;   // h fp8: 12.8 MB
// total ~77.2 MB

using f32x4  = __attribute__((ext_vector_type(4))) float;
using f32x2  = __attribute__((ext_vector_type(2))) float;
using short8 = __attribute__((ext_vector_type(8))) short;

__device__ __forceinline__ ushort f2bf(float f) {
    union { float f; unsigned u; } v; v.f = f;
    unsigned u = v.u;
    return (ushort)((u + 0x7fffu + ((u >> 16) & 1u)) >> 16);
}

// ---- fused setup: cast x->fp8 | pack weights | rowptrs ----
constexpr int CAST_BLKS = 200000 * IN_F / 8 / 256;  // 12500
constexpr int PACK_BLKS = 44;
constexpr int RP_BLKS   = (N_DST1 + N_DST2 + 2 + 255) / 256;  // 236

__global__ __launch_bounds__(256) void setup_all(
    const float* __restrict__ x, unsigned char* __restrict__ x8,
    const float* __restrict__ Ws1, const float* __restrict__ Wn1,
    const float* __restrict__ Ws2, const float* __restrict__ Wn2,
    ushort* __restrict__ bps, ushort* __restrict__ bpn, ushort* __restrict__ bp2,
    const int* __restrict__ dst1, const int* __restrict__ dst2,
    int* __restrict__ rp1, int* __restrict__ rp2) {
    int b = blockIdx.x;
    if (b < CAST_BLKS) {
        int i = b * 256 + threadIdx.x;  // groups of 8 floats
        float4 v0 = ((const float4*)x)[2 * i];
        float4 v1 = ((const float4*)x)[2 * i + 1];
        int p0 = __builtin_amdgcn_cvt_pk_fp8_f32(v0.x, v0.y, 0, false);
        p0     = __builtin_amdgcn_cvt_pk_fp8_f32(v0.z, v0.w, p0, true);
        int p1 = __builtin_amdgcn_cvt_pk_fp8_f32(v1.x, v1.y, 0, false);
        p1     = __builtin_amdgcn_cvt_pk_fp8_f32(v1.z, v1.w, p1, true);
        uint2 o; o.x = (unsigned)p0; o.y = (unsigned)p1;
        ((uint2*)x8)[i] = o;
    } else if (b < CAST_BLKS + PACK_BLKS) {
        int pb = b - CAST_BLKS;
        if (pb < 32) {
            const float* W = (pb < 16) ? Ws1 : Wn1;
            ushort* P      = (pb < 16) ? bps : bpn;
            int idx = (pb & 15) * 256 + threadIdx.x;  // 0..4095
            int lane = idx & 63, kb = (idx >> 6) & 3, nb = idx >> 8;
            int n  = nb * 16 + (lane & 15);
            int k0 = kb * 32 + ((lane >> 4) * 8);
            ushort tmp[8];
#pragma unroll
            for (int j = 0; j < 8; ++j) tmp[j] = f2bf(W[(k0 + j) * H_F + n]);
            ((uint4*)P)[idx] = *(uint4*)tmp;
        } else {
            int idx = (pb - 32) * 256 + threadIdx.x;  // 0..3071
            if (idx < 3072) {
                int lane = idx & 63, rem = idx >> 6;
                int nb = rem % 3, kb = rem / 3;
                int col = nb * 16 + (lane & 15);
                int k0  = (kb & 7) * 32 + ((lane >> 4) * 8);
                const float* W = (kb < 8) ? Ws2 : Wn2;
                ushort tmp[8];
#pragma unroll
                for (int j = 0; j < 8; ++j)
                    tmp[j] = (col < N_CLS) ? f2bf(W[(k0 + j) * N_CLS + col]) : (ushort)0;
                ((uint4*)bp2)[(kb * 3 + nb) * 64 + lane] = *(uint4*)tmp;
            }
        }
    } else {
        int idx = (b - CAST_BLKS - PACK_BLKS) * 256 + threadIdx.x;
        const int* dst; int* rp; int E; int target;
        if (idx <= N_DST1) { dst = dst1; rp = rp1; E = E1; target = idx; }
        else if (idx <= N_DST1 + 1 + N_DST2) {
            dst = dst2; rp = rp2; E = E2; target = idx - (N_DST1 + 1);
        } else return;
        int lo = 0, hi = E;
        while (lo < hi) {
            int mid = (lo + hi) >> 1;
            if (dst[mid] < target) lo = mid + 1; else hi = mid;
        }
        rp[target] = lo;
    }
}

// ---- fused layer 1: 16 waves, one dst per wave -> LDS, then MFMA tile ----
// Block = 1024 threads = 16 waves = 16 output rows.
// Phase A: wave w aggregates dst m0+w (8 edges per dwordx4 wave-load).
// Phase B: wave w computes cols [w*16, w*16+16) of the 16x256 tile.
__global__ __launch_bounds__(1024, 8) void fused1(
    const unsigned char* __restrict__ x8, const int* __restrict__ src,
    const int* __restrict__ rp, const float* __restrict__ x,
    const ushort* __restrict__ BpS, const ushort* __restrict__ BpN,
    const float* __restrict__ b1, ushort* __restrict__ hb,
    unsigned char* __restrict__ h8) {
    // row stride 136 shorts = 272 B: rows advance 4 banks -> worst 2-way (free)
    __shared__ ushort lhn[16][136];
    int tid = threadIdx.x;
    int wave = tid >> 6, lane = tid & 63;
    int m0 = blockIdx.x * 16;  // 3125 * 16 = 50000 exactly

    // ---- phase A: aggregation (one dst per wave) ----
    {
        const uint4* x4 = (const uint4*)x8;  // row stride 8 uint4
        int g = lane >> 3, c = lane & 7;
        int d = m0 + wave;
        int s = rp[d], e = rp[d + 1];
        int deg = e - s;
        float a[16] = {};
        auto acc16 = [&](uint4 v) {
            f32x2 f;
            f = __builtin_amdgcn_cvt_pk_f32_fp8((int)v.x, false); a[0]  += f[0]; a[1]  += f[1];
            f = __builtin_amdgcn_cvt_pk_f32_fp8((int)v.x, true);  a[2]  += f[0]; a[3]  += f[1];
            f = __builtin_amdgcn_cvt_pk_f32_fp8((int)v.y, false); a[4]  += f[0]; a[5]  += f[1];
            f = __builtin_amdgcn_cvt_pk_f32_fp8((int)v.y, true);  a[6]  += f[0]; a[7]  += f[1];
            f = __builtin_amdgcn_cvt_pk_f32_fp8((int)v.z, false); a[8]  += f[0]; a[9]  += f[1];
            f = __builtin_amdgcn_cvt_pk_f32_fp8((int)v.z, true);  a[10] += f[0]; a[11] += f[1];
            f = __builtin_amdgcn_cvt_pk_f32_fp8((int)v.w, false); a[12] += f[0]; a[13] += f[1];
            f = __builtin_amdgcn_cvt_pk_f32_fp8((int)v.w, true);  a[14] += f[0]; a[15] += f[1];
        };
        int nfull = deg >> 3;
        int j = 0;
        for (; j + 2 <= nfull; j += 2) {
            int e0 = src[s + 8 * j + g];
            int e1 = src[s + 8 * j + 8 + g];
            uint4 v0 = x4[(size_t)e0 * 8 + c];
            uint4 v1 = x4[(size_t)e1 * 8 + c];
            acc16(v0);
            acc16(v1);
        }
        for (; j < nfull; ++j) {
            int e0 = src[s + 8 * j + g];
            uint4 v = x4[(size_t)e0 * 8 + c];
            acc16(v);
        }
        int b0 = s + 8 * nfull;
        int n = e - b0;  // 0..7
        if (g < n) {
            int e0 = src[b0 + g];
            uint4 v = x4[(size_t)e0 * 8 + c];
            acc16(v);
        }
#pragma unroll
        for (int qq = 0; qq < 16; ++qq) {
            a[qq] += __shfl_xor(a[qq], 8);
            a[qq] += __shfl_xor(a[qq], 16);
            a[qq] += __shfl_xor(a[qq], 32);
        }
        if (lane < 8) {  // lane t owns features t*16..t*16+15
            float inv = 1.f / fmaxf((float)deg, 1.f);
            unsigned o[8];
#pragma unroll
            for (int p = 0; p < 8; ++p)
                o[p] = (unsigned)f2bf(a[2 * p] * inv) |
                       ((unsigned)f2bf(a[2 * p + 1] * inv) << 16);
            uint4* dp = (uint4*)&lhn[wave][lane * 16];
            dp[0] = make_uint4(o[0], o[1], o[2], o[3]);
            dp[1] = make_uint4(o[4], o[5], o[6], o[7]);
        }
    }
    __syncthreads();

    // ---- phase B: GEMM, wave w covers cols [w*16, w*16+16) ----
    int nb = wave;
    int mloc = lane & 15;
    int mrow = m0 + mloc;
    int koff = (lane >> 4) * 8;

    const float* Af = x + (size_t)mrow * IN_F;
    short8 a0[4], a1[4];
#pragma unroll
    for (int kb = 0; kb < 4; ++kb) {
        float4 q0 = *(const float4*)(Af + kb * 32 + koff);
        float4 q1 = *(const float4*)(Af + kb * 32 + koff + 4);
        a0[kb][0] = (short)f2bf(q0.x); a0[kb][1] = (short)f2bf(q0.y);
        a0[kb][2] = (short)f2bf(q0.z); a0[kb][3] = (short)f2bf(q0.w);
        a0[kb][4] = (short)f2bf(q1.x); a0[kb][5] = (short)f2bf(q1.y);
        a0[kb][6] = (short)f2bf(q1.z); a0[kb][7] = (short)f2bf(q1.w);
        a1[kb] = *(const short8*)&lhn[mloc][kb * 32 + koff];
    }

    f32x4 acc = (f32x4){0.f, 0.f, 0.f, 0.f};
#pragma unroll
    for (int kb = 0; kb < 4; ++kb) {
        short8 b = *(const short8*)(BpS + ((size_t)(nb * 4 + kb) * 64 + lane) * 8);
        acc = __builtin_amdgcn_mfma_f32_16x16x32_bf16(a0[kb], b, acc, 0, 0, 0);
    }
#pragma unroll
    for (int kb = 0; kb < 4; ++kb) {
        short8 b = *(const short8*)(BpN + ((size_t)(nb * 4 + kb) * 64 + lane) * 8);
        acc = __builtin_amdgcn_mfma_f32_16x16x32_bf16(a1[kb], b, acc, 0, 0, 0);
    }

    int crow0 = m0 + (lane >> 4) * 4;
    int ccol  = lane & 15;
    {
        size_t col = (size_t)nb * 16 + ccol;
        float bias = b1[col];
#pragma unroll
        for (int r = 0; r < 4; ++r) {
            int row = crow0 + r;
            float v = fmaxf(acc[r] + bias, 0.f);
            int p = __builtin_amdgcn_cvt_pk_fp8_f32(v, v, 0, false);
            h8[(size_t)row * H_F + col] = (unsigned char)(p & 0xff);
            if (row < N_DST2) hb[(size_t)row * H_F + col] = f2bf(v);
        }
    }
}

// ---- fused layer 2: 16 waves, one dst per wave -> LDS; K-split MFMA GEMM ----
// Block = 1024 threads = 16 output rows. Phase B on waves 0..3 (K=512 split
// 4 ways), partials reduced through LDS, wave 0 writes the 16x47 tile.
__global__ __launch_bounds__(1024, 8) void fused2(
    const unsigned char* __restrict__ h8, const int* __restrict__ src,
    const int* __restrict__ rp, const ushort* __restrict__ hb,
    const ushort* __restrict__ P2, const float* __restrict__ b2,
    float* __restrict__ out) {
    // row stride 264 shorts = 528 B: rows advance 4 banks -> worst 2-way (free)
    __shared__ ushort lhn[16][264];
    __shared__ float lred[3][3][64][4];  // waves 1..3 partial acc
    int tid = threadIdx.x;
    int wave = tid >> 6, lane = tid & 63;
    int m0 = blockIdx.x * 16;  // 625 * 16 = 10000 exactly

    // ---- phase A: aggregation (one dst per wave; 4 edges per wave-load) ----
    {
        const uint4* h4 = (const uint4*)h8;  // row stride 16 uint4
        int g = lane >> 4, c = lane & 15;
        int d = m0 + wave;
        int s = rp[d], e = rp[d + 1];
        int deg = e - s;
        float a[16] = {};
        auto acc16 = [&](uint4 v) {
            f32x2 f;
            f = __builtin_amdgcn_cvt_pk_f32_fp8((int)v.x, false); a[0]  += f[0]; a[1]  += f[1];
            f = __builtin_amdgcn_cvt_pk_f32_fp8((int)v.x, true);  a[2]  += f[0]; a[3]  += f[1];
            f = __builtin_amdgcn_cvt_pk_f32_fp8((int)v.y, false); a[4]  += f[0]; a[5]  += f[1];
            f = __builtin_amdgcn_cvt_pk_f32_fp8((int)v.y, true);  a[6]  += f[0]; a[7]  += f[1];
            f = __builtin_amdgcn_cvt_pk_f32_fp8((int)v.z, false); a[8]  += f[0]; a[9]  += f[1];
            f = __builtin_amdgcn_cvt_pk_f32_fp8((int)v.z, true);  a[10] += f[0]; a[11] += f[1];
            f = __builtin_amdgcn_cvt_pk_f32_fp8((int)v.w, false); a[12] += f[0]; a[13] += f[1];
            f = __builtin_amdgcn_cvt_pk_f32_fp8((int)v.w, true);  a[14] += f[0]; a[15] += f[1];
        };
        int nfull = deg >> 2;
        int j = 0;
        for (; j + 2 <= nfull; j += 2) {
            int e0 = src[s + 4 * j + g];
            int e1 = src[s + 4 * j + 4 + g];
            uint4 v0 = h4[(size_t)e0 * 16 + c];
            uint4 v1 = h4[(size_t)e1 * 16 + c];
            acc16(v0);
            acc16(v1);
        }
        for (; j < nfull; ++j) {
            int e0 = src[s + 4 * j + g];
            uint4 v = h4[(size_t)e0 * 16 + c];
            acc16(v);
        }
        int b0 = s + 4 * nfull;
        int n = e - b0;  // 0..3
        if (g < n) {
            int e0 = src[b0 + g];
            uint4 v = h4[(size_t)e0 * 16 + c];
            acc16(v);
        }
#pragma unroll
        for (int qq = 0; qq < 16; ++qq) {
            a[qq] += __shfl_xor(a[qq], 16);
            a[qq] += __shfl_xor(a[qq], 32);
        }
        if (lane < 16) {  // lane t owns features t*16..t*16+15
            float inv = 1.f / fmaxf((float)deg, 1.f);
            unsigned o[8];
#pragma unroll
            for (int p = 0; p < 8; ++p)
                o[p] = (unsigned)f2bf(a[2 * p] * inv) |
                       ((unsigned)f2bf(a[2 * p + 1] * inv) << 16);
            uint4* dp = (uint4*)&lhn[wave][lane * 16];
            dp[0] = make_uint4(o[0], o[1], o[2], o[3]);
            dp[1] = make_uint4(o[4], o[5], o[6], o[7]);
        }
    }
    __syncthreads();

    // ---- phase B: K-split GEMM on waves 0..3; wave w: kb = w*4..w*4+3 ----
    int mloc = lane & 15;
    int mrow = m0 + mloc;
    int koff = (lane >> 4) * 8;

    f32x4 acc[3];
#pragma unroll
    for (int nbq = 0; nbq < 3; ++nbq) acc[nbq] = (f32x4){0.f, 0.f, 0.f, 0.f};

    if (wave < 4) {
#pragma unroll
        for (int i = 0; i < 4; ++i) {
            int kb = wave * 4 + i;
            short8 a;
            if (wave < 2)
                a = *(const short8*)(hb + (size_t)mrow * H_F + kb * 32 + koff);
            else
                a = *(const short8*)&lhn[mloc][(kb - 8) * 32 + koff];
#pragma unroll
            for (int nbq = 0; nbq < 3; ++nbq) {
                short8 b = *(const short8*)(P2 + ((size_t)(kb * 3 + nbq) * 64 + lane) * 8);
                acc[nbq] = __builtin_amdgcn_mfma_f32_16x16x32_bf16(a, b, acc[nbq], 0, 0, 0);
            }
        }
        if (wave != 0) {
#pragma unroll
            for (int nbq = 0; nbq < 3; ++nbq)
#pragma unroll
                for (int r = 0; r < 4; ++r)
                    lred[wave - 1][nbq][lane][r] = acc[nbq][r];
        }
    }
    __syncthreads();
    if (wave == 0) {
        int crow0 = m0 + (lane >> 4) * 4;
        int ccol  = lane & 15;
#pragma unroll
        for (int nbq = 0; nbq < 3; ++nbq) {
            int col = nbq * 16 + ccol;
#pragma unroll
            for (int r = 0; r < 4; ++r)
                acc[nbq][r] += lred[0][nbq][lane][r] + lred[1][nbq][lane][r] +
                               lred[2][nbq][lane][r];
            if (col < N_CLS) {
                float bias = b2[col];
#pragma unroll
                for (int r = 0; r < 4; ++r)
                    out[(size_t)(crow0 + r) * N_CLS + col] = acc[nbq][r] + bias;
            }
        }
    }
}

extern "C" void kernel_launch(void* const* d_in, const int* in_sizes, int n_in,
                              void* d_out, int out_size, void* d_ws, size_t ws_size,
                              hipStream_t stream) {
    const float* x   = (const float*)d_in[0];
    const float* Ws1 = (const float*)d_in[1];
    const float* Wn1 = (const float*)d_in[2];
    const float* b1  = (const float*)d_in[3];
    const float* Ws2 = (const float*)d_in[4];
    const float* Wn2 = (const float*)d_in[5];
    const float* b2  = (const float*)d_in[6];
    const int* src1  = (const int*)d_in[7];
    const int* dst1  = (const int*)d_in[8];
    const int* src2  = (const int*)d_in[9];
    const int* dst2  = (const int*)d_in[10];
    float* out = (float*)d_out;

    char* ws = (char*)d_ws;
    int*           rp1 = (int*)(ws + RP1_OFF);
    int*           rp2 = (int*)(ws + RP2_OFF);
    ushort*        bps = (ushort*)(ws + BPS_OFF);
    ushort*        bpn = (ushort*)(ws + BPN_OFF);
    ushort*        bp2 = (ushort*)(ws + BP2_OFF);
    unsigned char* x8  = (unsigned char*)(ws + X8_OFF);
    ushort*        hb  = (ushort*)(ws + HB_OFF);
    unsigned char* h8  = (unsigned char*)(ws + H8_OFF);

    setup_all<<<CAST_BLKS + PACK_BLKS + RP_BLKS, 256, 0, stream>>>(
        x, x8, Ws1, Wn1, Ws2, Wn2, bps, bpn, bp2, dst1, dst2, rp1, rp2);
    fused1<<<N_DST1 / 16, 1024, 0, stream>>>(x8, src1, rp1, x, bps, bpn, b1, hb, h8);
    fused2<<<N_DST2 / 16, 1024, 0, stream>>>(h8, src2, rp2, hb, bp2, b2, out);
}

// Round 4
// 281.705 us; speedup vs baseline: 1.1616x; 1.1616x over previous
//
#include <hip/hip_runtime.h>

constexpr int N_DST1 = 50000;
constexpr int N_DST2 = 10000;
constexpr int E1     = 2000000;
constexpr int E2     = 400000;
constexpr int IN_F   = 128;
constexpr int H_F    = 256;
constexpr int N_CLS  = 47;

// Workspace layout (bytes)
constexpr size_t RP1_OFF = 0;          // 50001 int
constexpr size_t RP2_OFF = 204800;     // 10001 int
constexpr size_t BPS_OFF = 245760;     // Ws1 packed bf16 frags: 64 KB
constexpr size_t BPN_OFF = 311296;     // Wn1 packed: 64 KB
constexpr size_t BP2_OFF = 376832;     // [Ws2;Wn2] packed: 48 KB
constexpr size_t X8_OFF  = 430080;     // x fp8: 200000*128 = 25.6 MB
constexpr size_t HN1_OFF = 26030080;   // hn1 bf16: 12.8 MB
constexpr size_t HB_OFF  = 38830080;   // h bf16 (rows < N_DST2 used)
constexpr size_t H8_OFF  = 64430080;   // h fp8: 12.8 MB
constexpr size_t HN2_OFF = 77230080;   // hn2 bf16: 5.12 MB
// total ~82.4 MB

using f32x4  = __attribute__((ext_vector_type(4))) float;
using f32x2  = __attribute__((ext_vector_type(2))) float;
using short8 = __attribute__((ext_vector_type(8))) short;

__device__ __forceinline__ ushort f2bf(float f) {
    union { float f; unsigned u; } v; v.f = f;
    unsigned u = v.u;
    return (ushort)((u + 0x7fffu + ((u >> 16) & 1u)) >> 16);
}

// ---- fused setup: cast x->fp8 | pack weights | rowptrs ----
constexpr int CAST_BLKS = 200000 * IN_F / 8 / 256;  // 12500
constexpr int PACK_BLKS = 44;
constexpr int RP_BLKS   = (N_DST1 + N_DST2 + 2 + 255) / 256;  // 236

__global__ __launch_bounds__(256) void setup_all(
    const float* __restrict__ x, unsigned char* __restrict__ x8,
    const float* __restrict__ Ws1, const float* __restrict__ Wn1,
    const float* __restrict__ Ws2, const float* __restrict__ Wn2,
    ushort* __restrict__ bps, ushort* __restrict__ bpn, ushort* __restrict__ bp2,
    const int* __restrict__ dst1, const int* __restrict__ dst2,
    int* __restrict__ rp1, int* __restrict__ rp2) {
    int b = blockIdx.x;
    if (b < CAST_BLKS) {
        int i = b * 256 + threadIdx.x;  // groups of 8 floats
        float4 v0 = ((const float4*)x)[2 * i];
        float4 v1 = ((const float4*)x)[2 * i + 1];
        int p0 = __builtin_amdgcn_cvt_pk_fp8_f32(v0.x, v0.y, 0, false);
        p0     = __builtin_amdgcn_cvt_pk_fp8_f32(v0.z, v0.w, p0, true);
        int p1 = __builtin_amdgcn_cvt_pk_fp8_f32(v1.x, v1.y, 0, false);
        p1     = __builtin_amdgcn_cvt_pk_fp8_f32(v1.z, v1.w, p1, true);
        uint2 o; o.x = (unsigned)p0; o.y = (unsigned)p1;
        ((uint2*)x8)[i] = o;
    } else if (b < CAST_BLKS + PACK_BLKS) {
        int pb = b - CAST_BLKS;
        if (pb < 32) {
            const float* W = (pb < 16) ? Ws1 : Wn1;
            ushort* P      = (pb < 16) ? bps : bpn;
            int idx = (pb & 15) * 256 + threadIdx.x;  // 0..4095
            int lane = idx & 63, kb = (idx >> 6) & 3, nb = idx >> 8;
            int n  = nb * 16 + (lane & 15);
            int k0 = kb * 32 + ((lane >> 4) * 8);
            ushort tmp[8];
#pragma unroll
            for (int j = 0; j < 8; ++j) tmp[j] = f2bf(W[(k0 + j) * H_F + n]);
            ((uint4*)P)[idx] = *(uint4*)tmp;
        } else {
            int idx = (pb - 32) * 256 + threadIdx.x;  // 0..3071
            if (idx < 3072) {
                int lane = idx & 63, rem = idx >> 6;
                int nb = rem % 3, kb = rem / 3;
                int col = nb * 16 + (lane & 15);
                int k0  = (kb & 7) * 32 + ((lane >> 4) * 8);
                const float* W = (kb < 8) ? Ws2 : Wn2;
                ushort tmp[8];
#pragma unroll
                for (int j = 0; j < 8; ++j)
                    tmp[j] = (col < N_CLS) ? f2bf(W[(k0 + j) * N_CLS + col]) : (ushort)0;
                ((uint4*)bp2)[(kb * 3 + nb) * 64 + lane] = *(uint4*)tmp;
            }
        }
    } else {
        int idx = (b - CAST_BLKS - PACK_BLKS) * 256 + threadIdx.x;
        const int* dst; int* rp; int E; int target;
        if (idx <= N_DST1) { dst = dst1; rp = rp1; E = E1; target = idx; }
        else if (idx <= N_DST1 + 1 + N_DST2) {
            dst = dst2; rp = rp2; E = E2; target = idx - (N_DST1 + 1);
        } else return;
        int lo = 0, hi = E;
        while (lo < hi) {
            int mid = (lo + hi) >> 1;
            if (dst[mid] < target) lo = mid + 1; else hi = mid;
        }
        rp[target] = lo;
    }
}

// ---- layer-1 mean agg: one wave/dst; idx preload + shfl distribute ----
// x8 row = 128 B = 8 uint4. lane t: edge-slot g=t>>3, chunk c=t&7 (16 B).
// Edge indices for up to 64 edges loaded in ONE coalesced 4B/lane load,
// then distributed per gather-step via __shfl -> src load off critical path,
// 4 outstanding gathers per lane. NOTE: every __shfl executes with all 64
// lanes active (shfl from an exec-masked lane is undefined on CDNA).
__global__ __launch_bounds__(256) void agg1b(const unsigned char* __restrict__ x8,
                                             const int* __restrict__ src,
                                             const int* __restrict__ rp,
                                             ushort* __restrict__ hn) {
    int t = threadIdx.x & 63;
    int d = blockIdx.x * 4 + (threadIdx.x >> 6);
    int s = rp[d], e = rp[d + 1];
    int deg = e - s;
    const uint4* x4 = (const uint4*)x8;  // row stride 8 uint4
    int g = t >> 3, c = t & 7;
    f32x2 a2[8] = {};
    auto accv = [&](uint4 v) {
        a2[0] += __builtin_amdgcn_cvt_pk_f32_fp8((int)v.x, false);
        a2[1] += __builtin_amdgcn_cvt_pk_f32_fp8((int)v.x, true);
        a2[2] += __builtin_amdgcn_cvt_pk_f32_fp8((int)v.y, false);
        a2[3] += __builtin_amdgcn_cvt_pk_f32_fp8((int)v.y, true);
        a2[4] += __builtin_amdgcn_cvt_pk_f32_fp8((int)v.z, false);
        a2[5] += __builtin_amdgcn_cvt_pk_f32_fp8((int)v.z, true);
        a2[6] += __builtin_amdgcn_cvt_pk_f32_fp8((int)v.w, false);
        a2[7] += __builtin_amdgcn_cvt_pk_f32_fp8((int)v.w, true);
    };
    for (int b0 = s; b0 < e; b0 += 64) {
        int nb = min(64, e - b0);
        int idx = 0;
        if (t < nb) idx = src[b0 + t];  // coalesced
        int nfull = nb >> 3;
        int j = 0;
        for (; j + 4 <= nfull; j += 4) {
            int e0 = __shfl(idx, (j + 0) * 8 + g);
            int e1 = __shfl(idx, (j + 1) * 8 + g);
            int e2 = __shfl(idx, (j + 2) * 8 + g);
            int e3 = __shfl(idx, (j + 3) * 8 + g);
            uint4 v0 = x4[(size_t)e0 * 8 + c];
            uint4 v1 = x4[(size_t)e1 * 8 + c];
            uint4 v2 = x4[(size_t)e2 * 8 + c];
            uint4 v3 = x4[(size_t)e3 * 8 + c];
            accv(v0); accv(v1); accv(v2); accv(v3);
        }
        for (; j < nfull; ++j) {
            int e0 = __shfl(idx, j * 8 + g);
            uint4 v = x4[(size_t)e0 * 8 + c];
            accv(v);
        }
        int rem = nb & 7;
        int er = __shfl(idx, (nfull * 8 + g) & 63);  // all lanes active here
        if (g < rem) {
            uint4 v = x4[(size_t)er * 8 + c];
            accv(v);
        }
    }
    // reduce over edge-slots g (lanes xor 8,16,32)
#pragma unroll
    for (int q = 0; q < 8; ++q) {
#pragma unroll
        for (int h = 0; h < 2; ++h) {
            float av = a2[q][h];
            av += __shfl_xor(av, 8);
            av += __shfl_xor(av, 16);
            av += __shfl_xor(av, 32);
            a2[q][h] = av;
        }
    }
    if (t < 8) {  // lane c==t owns features t*16..t*16+15
        float inv = 1.f / fmaxf((float)deg, 1.f);
        unsigned o[8];
#pragma unroll
        for (int p = 0; p < 8; ++p)
            o[p] = (unsigned)f2bf(a2[p][0] * inv) |
                   ((unsigned)f2bf(a2[p][1] * inv) << 16);
        uint4* hrow = (uint4*)hn + (size_t)d * 16 + t * 2;  // row = 16 uint4
        hrow[0] = make_uint4(o[0], o[1], o[2], o[3]);
        hrow[1] = make_uint4(o[4], o[5], o[6], o[7]);
    }
}

// ---- layer-2 mean agg: one wave/dst; idx preload + shfl distribute ----
// h8 row = 256 B = 16 uint4. lane t: edge-slot g=t>>4, chunk c=t&15.
__global__ __launch_bounds__(256) void agg2b(const unsigned char* __restrict__ h8,
                                             const int* __restrict__ src,
                                             const int* __restrict__ rp,
                                             ushort* __restrict__ hn) {
    int t = threadIdx.x & 63;
    int d = blockIdx.x * 4 + (threadIdx.x >> 6);
    int s = rp[d], e = rp[d + 1];
    int deg = e - s;
    const uint4* h4 = (const uint4*)h8;  // row stride 16 uint4
    int g = t >> 4, c = t & 15;
    f32x2 a2[8] = {};
    auto accv = [&](uint4 v) {
        a2[0] += __builtin_amdgcn_cvt_pk_f32_fp8((int)v.x, false);
        a2[1] += __builtin_amdgcn_cvt_pk_f32_fp8((int)v.x, true);
        a2[2] += __builtin_amdgcn_cvt_pk_f32_fp8((int)v.y, false);
        a2[3] += __builtin_amdgcn_cvt_pk_f32_fp8((int)v.y, true);
        a2[4] += __builtin_amdgcn_cvt_pk_f32_fp8((int)v.z, false);
        a2[5] += __builtin_amdgcn_cvt_pk_f32_fp8((int)v.z, true);
        a2[6] += __builtin_amdgcn_cvt_pk_f32_fp8((int)v.w, false);
        a2[7] += __builtin_amdgcn_cvt_pk_f32_fp8((int)v.w, true);
    };
    for (int b0 = s; b0 < e; b0 += 64) {
        int nb = min(64, e - b0);
        int idx = 0;
        if (t < nb) idx = src[b0 + t];  // coalesced
        int nfull = nb >> 2;
        int j = 0;
        for (; j + 4 <= nfull; j += 4) {
            int e0 = __shfl(idx, (j + 0) * 4 + g);
            int e1 = __shfl(idx, (j + 1) * 4 + g);
            int e2 = __shfl(idx, (j + 2) * 4 + g);
            int e3 = __shfl(idx, (j + 3) * 4 + g);
            uint4 v0 = h4[(size_t)e0 * 16 + c];
            uint4 v1 = h4[(size_t)e1 * 16 + c];
            uint4 v2 = h4[(size_t)e2 * 16 + c];
            uint4 v3 = h4[(size_t)e3 * 16 + c];
            accv(v0); accv(v1); accv(v2); accv(v3);
        }
        for (; j < nfull; ++j) {
            int e0 = __shfl(idx, j * 4 + g);
            uint4 v = h4[(size_t)e0 * 16 + c];
            accv(v);
        }
        int rem = nb & 3;
        int er = __shfl(idx, (nfull * 4 + g) & 63);  // all lanes active here
        if (g < rem) {
            uint4 v = h4[(size_t)er * 16 + c];
            accv(v);
        }
    }
    // reduce over edge-slots g (lanes xor 16,32)
#pragma unroll
    for (int q = 0; q < 8; ++q) {
#pragma unroll
        for (int h = 0; h < 2; ++h) {
            float av = a2[q][h];
            av += __shfl_xor(av, 16);
            av += __shfl_xor(av, 32);
            a2[q][h] = av;
        }
    }
    if (t < 16) {  // lane c==t owns features t*16..t*16+15
        float inv = 1.f / fmaxf((float)deg, 1.f);
        unsigned o[8];
#pragma unroll
        for (int p = 0; p < 8; ++p)
            o[p] = (unsigned)f2bf(a2[p][0] * inv) |
                   ((unsigned)f2bf(a2[p][1] * inv) << 16);
        uint4* hrow = (uint4*)hn + (size_t)d * 32 + t * 2;  // row = 32 uint4
        hrow[0] = make_uint4(o[0], o[1], o[2], o[3]);
        hrow[1] = make_uint4(o[4], o[5], o[6], o[7]);
    }
}

// ---- layer 1 GEMM: barrier-free, one wave = 16 rows x 64 cols; B from L2 ----
// 3125 blocks x 4 waves; wave w covers cols [w*64, w*64+64).
__global__ __launch_bounds__(256) void gemm1_mfma(
    const float* __restrict__ x, const ushort* __restrict__ hn1,
    const ushort* __restrict__ BpS, const ushort* __restrict__ BpN,
    const float* __restrict__ b1, ushort* __restrict__ hb,
    unsigned char* __restrict__ h8) {
    int tid = threadIdx.x;
    int wave = tid >> 6, lane = tid & 63;
    int m0 = blockIdx.x * 16;            // 3125 * 16 = 50000 exactly
    int nb0 = wave * 4;                  // 4 nb blocks of 16 cols each
    int mloc = lane & 15;
    int mrow = m0 + mloc;
    int koff = (lane >> 4) * 8;

    // hoisted A fragments: ph0 = x (fp32->bf16), ph1 = hn1 (bf16)
    const float*  Af = x   + (size_t)mrow * IN_F;
    const ushort* Ah = hn1 + (size_t)mrow * IN_F;
    short8 a0[4], a1[4];
#pragma unroll
    for (int kb = 0; kb < 4; ++kb) {
        float4 q0 = *(const float4*)(Af + kb * 32 + koff);
        float4 q1 = *(const float4*)(Af + kb * 32 + koff + 4);
        a0[kb][0] = (short)f2bf(q0.x); a0[kb][1] = (short)f2bf(q0.y);
        a0[kb][2] = (short)f2bf(q0.z); a0[kb][3] = (short)f2bf(q0.w);
        a0[kb][4] = (short)f2bf(q1.x); a0[kb][5] = (short)f2bf(q1.y);
        a0[kb][6] = (short)f2bf(q1.z); a0[kb][7] = (short)f2bf(q1.w);
        a1[kb] = *(const short8*)(Ah + kb * 32 + koff);
    }

    f32x4 acc[4];
#pragma unroll
    for (int nb = 0; nb < 4; ++nb) acc[nb] = (f32x4){0.f, 0.f, 0.f, 0.f};

#pragma unroll
    for (int kb = 0; kb < 4; ++kb)
#pragma unroll
        for (int nb = 0; nb < 4; ++nb) {
            short8 b = *(const short8*)(BpS + ((size_t)((nb0 + nb) * 4 + kb) * 64 + lane) * 8);
            acc[nb] = __builtin_amdgcn_mfma_f32_16x16x32_bf16(a0[kb], b, acc[nb], 0, 0, 0);
        }
#pragma unroll
    for (int kb = 0; kb < 4; ++kb)
#pragma unroll
        for (int nb = 0; nb < 4; ++nb) {
            short8 b = *(const short8*)(BpN + ((size_t)((nb0 + nb) * 4 + kb) * 64 + lane) * 8);
            acc[nb] = __builtin_amdgcn_mfma_f32_16x16x32_bf16(a1[kb], b, acc[nb], 0, 0, 0);
        }

    int crow0 = m0 + (lane >> 4) * 4;
    int ccol  = lane & 15;
#pragma unroll
    for (int nb = 0; nb < 4; ++nb) {
        size_t col = (size_t)(nb0 + nb) * 16 + ccol;
        float bias = b1[col];
#pragma unroll
        for (int r = 0; r < 4; ++r) {
            int row = crow0 + r;
            float v = fmaxf(acc[nb][r] + bias, 0.f);
            int p = __builtin_amdgcn_cvt_pk_fp8_f32(v, v, 0, false);
            h8[(size_t)row * H_F + col] = (unsigned char)(p & 0xff);
            if (row < N_DST2) hb[(size_t)row * H_F + col] = f2bf(v);
        }
    }
}

// ---- layer 2 GEMM (MFMA, K=512 over [hb|hn2], N padded to 48) ----
__global__ __launch_bounds__(256) void gemm2_mfma(
    const ushort* __restrict__ hb, const ushort* __restrict__ hn2,
    const ushort* __restrict__ P2, const float* __restrict__ b2,
    float* __restrict__ out) {
    int tid = threadIdx.x;
    int wave = tid >> 6, lane = tid & 63;
    int m0 = (blockIdx.x * 4 + wave) * 16;
    if (m0 >= N_DST2) return;
    int mrow = m0 + (lane & 15);
    int koff = (lane >> 4) * 8;

    f32x4 acc[3];
#pragma unroll
    for (int nb = 0; nb < 3; ++nb) acc[nb] = (f32x4){0.f, 0.f, 0.f, 0.f};

#pragma unroll
    for (int kb = 0; kb < 16; ++kb) {
        const ushort* A = (kb < 8)
            ? (hb  + (size_t)mrow * H_F + kb * 32 + koff)
            : (hn2 + (size_t)mrow * H_F + (kb - 8) * 32 + koff);
        short8 a = *(const short8*)A;
#pragma unroll
        for (int nb = 0; nb < 3; ++nb) {
            short8 b = *(const short8*)(P2 + ((size_t)(kb * 3 + nb) * 64 + lane) * 8);
            acc[nb] = __builtin_amdgcn_mfma_f32_16x16x32_bf16(a, b, acc[nb], 0, 0, 0);
        }
    }
    int crow0 = m0 + (lane >> 4) * 4;
    int ccol  = lane & 15;
#pragma unroll
    for (int nb = 0; nb < 3; ++nb) {
        int col = nb * 16 + ccol;
        if (col < N_CLS) {
            float bias = b2[col];
#pragma unroll
            for (int r = 0; r < 4; ++r)
                out[(size_t)(crow0 + r) * N_CLS + col] = acc[nb][r] + bias;
        }
    }
}

extern "C" void kernel_launch(void* const* d_in, const int* in_sizes, int n_in,
                              void* d_out, int out_size, void* d_ws, size_t ws_size,
                              hipStream_t stream) {
    const float* x   = (const float*)d_in[0];
    const float* Ws1 = (const float*)d_in[1];
    const float* Wn1 = (const float*)d_in[2];
    const float* b1  = (const float*)d_in[3];
    const float* Ws2 = (const float*)d_in[4];
    const float* Wn2 = (const float*)d_in[5];
    const float* b2  = (const float*)d_in[6];
    const int* src1  = (const int*)d_in[7];
    const int* dst1  = (const int*)d_in[8];
    const int* src2  = (const int*)d_in[9];
    const int* dst2  = (const int*)d_in[10];
    float* out = (float*)d_out;

    char* ws = (char*)d_ws;
    int*           rp1 = (int*)(ws + RP1_OFF);
    int*           rp2 = (int*)(ws + RP2_OFF);
    ushort*        bps = (ushort*)(ws + BPS_OFF);
    ushort*        bpn = (ushort*)(ws + BPN_OFF);
    ushort*        bp2 = (ushort*)(ws + BP2_OFF);
    unsigned char* x8  = (unsigned char*)(ws + X8_OFF);
    ushort*        hn1 = (ushort*)(ws + HN1_OFF);
    ushort*        hb  = (ushort*)(ws + HB_OFF);
    unsigned char* h8  = (unsigned char*)(ws + H8_OFF);
    ushort*        hn2 = (ushort*)(ws + HN2_OFF);

    setup_all<<<CAST_BLKS + PACK_BLKS + RP_BLKS, 256, 0, stream>>>(
        x, x8, Ws1, Wn1, Ws2, Wn2, bps, bpn, bp2, dst1, dst2, rp1, rp2);
    agg1b<<<N_DST1 / 4, 256, 0, stream>>>(x8, src1, rp1, hn1);
    gemm1_mfma<<<N_DST1 / 16, 256, 0, stream>>>(x, hn1, bps, bpn, b1, hb, h8);
    agg2b<<<N_DST2 / 4, 256, 0, stream>>>(h8, src2, rp2, hn2);
    gemm2_mfma<<<(N_DST2 / 16 + 3) / 4, 256, 0, stream>>>(hb, hn2, bp2, b2, out);
}

// Round 6
// 276.043 us; speedup vs baseline: 1.1854x; 1.0205x over previous
//
#include <hip/hip_runtime.h>

constexpr int N_DST1 = 50000;
constexpr int N_DST2 = 10000;
constexpr int E1     = 2000000;
constexpr int E2     = 400000;
constexpr int IN_F   = 128;
constexpr int H_F    = 256;
constexpr int N_CLS  = 47;

// Workspace layout (bytes)
constexpr size_t RP1_OFF = 0;          // 50001 int
constexpr size_t RP2_OFF = 204800;     // 10001 int
constexpr size_t BPS_OFF = 245760;     // Ws1 packed bf16 frags: 64 KB
constexpr size_t BPN_OFF = 311296;     // Wn1 packed: 64 KB
constexpr size_t BP2_OFF = 376832;     // [Ws2;Wn2] packed: 48 KB
constexpr size_t X8_OFF  = 430080;     // x fp8: 200000*128 = 25.6 MB
constexpr size_t HN1_OFF = 26030080;   // hn1 bf16: 12.8 MB
constexpr size_t HB_OFF  = 38830080;   // h bf16 (rows < N_DST2 used)
constexpr size_t Y_OFF   = 64430080;   // y = relu(h)@Wn2, bf16 [50000][64]: 6.4 MB
constexpr size_t YAGG_OFF= 77230080;   // yagg f32 [10000][64]: 2.56 MB
// total ~79.8 MB

using f32x4  = __attribute__((ext_vector_type(4))) float;
using f32x2  = __attribute__((ext_vector_type(2))) float;
using short8 = __attribute__((ext_vector_type(8))) short;

__device__ __forceinline__ ushort f2bf(float f) {
    union { float f; unsigned u; } v; v.f = f;
    unsigned u = v.u;
    return (ushort)((u + 0x7fffu + ((u >> 16) & 1u)) >> 16);
}

__device__ __forceinline__ float bflo(unsigned x) {
    union { unsigned q; float f; } w; w.q = x << 16; return w.f;
}
__device__ __forceinline__ float bfhi(unsigned x) {
    union { unsigned q; float f; } w; w.q = x & 0xffff0000u; return w.f;
}

// ---- fused setup: cast x->fp8 | pack weights | rowptrs ----
constexpr int CAST_BLKS = 200000 * IN_F / 8 / 256;  // 12500
constexpr int PACK_BLKS = 44;
constexpr int RP_BLKS   = (N_DST1 + N_DST2 + 2 + 255) / 256;  // 236

__global__ __launch_bounds__(256) void setup_all(
    const float* __restrict__ x, unsigned char* __restrict__ x8,
    const float* __restrict__ Ws1, const float* __restrict__ Wn1,
    const float* __restrict__ Ws2, const float* __restrict__ Wn2,
    ushort* __restrict__ bps, ushort* __restrict__ bpn, ushort* __restrict__ bp2,
    const int* __restrict__ dst1, const int* __restrict__ dst2,
    int* __restrict__ rp1, int* __restrict__ rp2) {
    int b = blockIdx.x;
    if (b < CAST_BLKS) {
        int i = b * 256 + threadIdx.x;  // groups of 8 floats
        float4 v0 = ((const float4*)x)[2 * i];
        float4 v1 = ((const float4*)x)[2 * i + 1];
        int p0 = __builtin_amdgcn_cvt_pk_fp8_f32(v0.x, v0.y, 0, false);
        p0     = __builtin_amdgcn_cvt_pk_fp8_f32(v0.z, v0.w, p0, true);
        int p1 = __builtin_amdgcn_cvt_pk_fp8_f32(v1.x, v1.y, 0, false);
        p1     = __builtin_amdgcn_cvt_pk_fp8_f32(v1.z, v1.w, p1, true);
        uint2 o; o.x = (unsigned)p0; o.y = (unsigned)p1;
        ((uint2*)x8)[i] = o;
    } else if (b < CAST_BLKS + PACK_BLKS) {
        int pb = b - CAST_BLKS;
        if (pb < 32) {
            const float* W = (pb < 16) ? Ws1 : Wn1;
            ushort* P      = (pb < 16) ? bps : bpn;
            int idx = (pb & 15) * 256 + threadIdx.x;  // 0..4095
            int lane = idx & 63, kb = (idx >> 6) & 3, nb = idx >> 8;
            int n  = nb * 16 + (lane & 15);
            int k0 = kb * 32 + ((lane >> 4) * 8);
            ushort tmp[8];
#pragma unroll
            for (int j = 0; j < 8; ++j) tmp[j] = f2bf(W[(k0 + j) * H_F + n]);
            ((uint4*)P)[idx] = *(uint4*)tmp;
        } else {
            int idx = (pb - 32) * 256 + threadIdx.x;  // 0..3071
            if (idx < 3072) {
                int lane = idx & 63, rem = idx >> 6;
                int nb = rem % 3, kb = rem / 3;
                int col = nb * 16 + (lane & 15);
                int k0  = (kb & 7) * 32 + ((lane >> 4) * 8);
                const float* W = (kb < 8) ? Ws2 : Wn2;
                ushort tmp[8];
#pragma unroll
                for (int j = 0; j < 8; ++j)
                    tmp[j] = (col < N_CLS) ? f2bf(W[(k0 + j) * N_CLS + col]) : (ushort)0;
                ((uint4*)bp2)[(kb * 3 + nb) * 64 + lane] = *(uint4*)tmp;
            }
        }
    } else {
        int idx = (b - CAST_BLKS - PACK_BLKS) * 256 + threadIdx.x;
        const int* dst; int* rp; int E; int target;
        if (idx <= N_DST1) { dst = dst1; rp = rp1; E = E1; target = idx; }
        else if (idx <= N_DST1 + 1 + N_DST2) {
            dst = dst2; rp = rp2; E = E2; target = idx - (N_DST1 + 1);
        } else return;
        int lo = 0, hi = E;
        while (lo < hi) {
            int mid = (lo + hi) >> 1;
            if (dst[mid] < target) lo = mid + 1; else hi = mid;
        }
        rp[target] = lo;
    }
}

// ---- layer-1 mean agg: one wave/dst; idx preload + shfl distribute ----
// x8 row = 128 B = 8 uint4. lane t: edge-slot g=t>>3, chunk c=t&7 (16 B).
// NOTE: every __shfl executes with all 64 lanes active (shfl from an
// exec-masked lane is undefined on CDNA).
__global__ __launch_bounds__(256) void agg1b(const unsigned char* __restrict__ x8,
                                             const int* __restrict__ src,
                                             const int* __restrict__ rp,
                                             ushort* __restrict__ hn) {
    int t = threadIdx.x & 63;
    int d = blockIdx.x * 4 + (threadIdx.x >> 6);
    int s = rp[d], e = rp[d + 1];
    int deg = e - s;
    const uint4* x4 = (const uint4*)x8;  // row stride 8 uint4
    int g = t >> 3, c = t & 7;
    f32x2 a2[8] = {};
    auto accv = [&](uint4 v) {
        a2[0] += __builtin_amdgcn_cvt_pk_f32_fp8((int)v.x, false);
        a2[1] += __builtin_amdgcn_cvt_pk_f32_fp8((int)v.x, true);
        a2[2] += __builtin_amdgcn_cvt_pk_f32_fp8((int)v.y, false);
        a2[3] += __builtin_amdgcn_cvt_pk_f32_fp8((int)v.y, true);
        a2[4] += __builtin_amdgcn_cvt_pk_f32_fp8((int)v.z, false);
        a2[5] += __builtin_amdgcn_cvt_pk_f32_fp8((int)v.z, true);
        a2[6] += __builtin_amdgcn_cvt_pk_f32_fp8((int)v.w, false);
        a2[7] += __builtin_amdgcn_cvt_pk_f32_fp8((int)v.w, true);
    };
    for (int b0 = s; b0 < e; b0 += 64) {
        int nb = min(64, e - b0);
        int idx = 0;
        if (t < nb) idx = src[b0 + t];  // coalesced
        int nfull = nb >> 3;
        int j = 0;
        for (; j + 4 <= nfull; j += 4) {
            int e0 = __shfl(idx, (j + 0) * 8 + g);
            int e1 = __shfl(idx, (j + 1) * 8 + g);
            int e2 = __shfl(idx, (j + 2) * 8 + g);
            int e3 = __shfl(idx, (j + 3) * 8 + g);
            uint4 v0 = x4[(size_t)e0 * 8 + c];
            uint4 v1 = x4[(size_t)e1 * 8 + c];
            uint4 v2 = x4[(size_t)e2 * 8 + c];
            uint4 v3 = x4[(size_t)e3 * 8 + c];
            accv(v0); accv(v1); accv(v2); accv(v3);
        }
        for (; j < nfull; ++j) {
            int e0 = __shfl(idx, j * 8 + g);
            uint4 v = x4[(size_t)e0 * 8 + c];
            accv(v);
        }
        int rem = nb & 7;
        int er = __shfl(idx, (nfull * 8 + g) & 63);  // all lanes active here
        if (g < rem) {
            uint4 v = x4[(size_t)er * 8 + c];
            accv(v);
        }
    }
    // reduce over edge-slots g (lanes xor 8,16,32)
#pragma unroll
    for (int q = 0; q < 8; ++q) {
#pragma unroll
        for (int h = 0; h < 2; ++h) {
            float av = a2[q][h];
            av += __shfl_xor(av, 8);
            av += __shfl_xor(av, 16);
            av += __shfl_xor(av, 32);
            a2[q][h] = av;
        }
    }
    if (t < 8) {  // lane c==t owns features t*16..t*16+15
        float inv = 1.f / fmaxf((float)deg, 1.f);
        unsigned o[8];
#pragma unroll
        for (int p = 0; p < 8; ++p)
            o[p] = (unsigned)f2bf(a2[p][0] * inv) |
                   ((unsigned)f2bf(a2[p][1] * inv) << 16);
        uint4* hrow = (uint4*)hn + (size_t)d * 16 + t * 2;  // row = 16 uint4
        hrow[0] = make_uint4(o[0], o[1], o[2], o[3]);
        hrow[1] = make_uint4(o[4], o[5], o[6], o[7]);
    }
}

// ---- layer 1 GEMM + fused y-projection ----
// Phase 1 (barrier-free): wave w computes h tile cols [w*64, w*64+64),
// writes hb (rows<N_DST2), stages relu(h) bf16 tile to LDS.
// Phase 2: y = relu(h) @ Wn2 (K=256 split 4 ways), LDS reduce, wave 0
// writes y rows (64 bf16 cols: 47 data + zero pad).
__global__ __launch_bounds__(256) void gemm1_mfma(
    const float* __restrict__ x, const ushort* __restrict__ hn1,
    const ushort* __restrict__ BpS, const ushort* __restrict__ BpN,
    const ushort* __restrict__ P2, const float* __restrict__ b1,
    ushort* __restrict__ hb, ushort* __restrict__ y) {
    __shared__ ushort lh[16][264];          // relu(h) tile, 2-way-free stride
    __shared__ f32x4 pred[3][3][64];        // waves 1..3 y partials
    int tid = threadIdx.x;
    int wave = tid >> 6, lane = tid & 63;
    int m0 = blockIdx.x * 16;            // 3125 * 16 = 50000 exactly
    int nb0 = wave * 4;                  // 4 nb blocks of 16 cols each
    int mloc = lane & 15;
    int mrow = m0 + mloc;
    int koff = (lane >> 4) * 8;

    // hoisted A fragments: ph0 = x (fp32->bf16), ph1 = hn1 (bf16)
    const float*  Af = x   + (size_t)mrow * IN_F;
    const ushort* Ah = hn1 + (size_t)mrow * IN_F;
    short8 a0[4], a1[4];
#pragma unroll
    for (int kb = 0; kb < 4; ++kb) {
        float4 q0 = *(const float4*)(Af + kb * 32 + koff);
        float4 q1 = *(const float4*)(Af + kb * 32 + koff + 4);
        a0[kb][0] = (short)f2bf(q0.x); a0[kb][1] = (short)f2bf(q0.y);
        a0[kb][2] = (short)f2bf(q0.z); a0[kb][3] = (short)f2bf(q0.w);
        a0[kb][4] = (short)f2bf(q1.x); a0[kb][5] = (short)f2bf(q1.y);
        a0[kb][6] = (short)f2bf(q1.z); a0[kb][7] = (short)f2bf(q1.w);
        a1[kb] = *(const short8*)(Ah + kb * 32 + koff);
    }

    f32x4 acc[4];
#pragma unroll
    for (int nb = 0; nb < 4; ++nb) acc[nb] = (f32x4){0.f, 0.f, 0.f, 0.f};

#pragma unroll
    for (int kb = 0; kb < 4; ++kb)
#pragma unroll
        for (int nb = 0; nb < 4; ++nb) {
            short8 b = *(const short8*)(BpS + ((size_t)((nb0 + nb) * 4 + kb) * 64 + lane) * 8);
            acc[nb] = __builtin_amdgcn_mfma_f32_16x16x32_bf16(a0[kb], b, acc[nb], 0, 0, 0);
        }
#pragma unroll
    for (int kb = 0; kb < 4; ++kb)
#pragma unroll
        for (int nb = 0; nb < 4; ++nb) {
            short8 b = *(const short8*)(BpN + ((size_t)((nb0 + nb) * 4 + kb) * 64 + lane) * 8);
            acc[nb] = __builtin_amdgcn_mfma_f32_16x16x32_bf16(a1[kb], b, acc[nb], 0, 0, 0);
        }

    int crow0 = (lane >> 4) * 4;         // local row base
    int ccol  = lane & 15;
#pragma unroll
    for (int nb = 0; nb < 4; ++nb) {
        size_t col = (size_t)(nb0 + nb) * 16 + ccol;
        float bias = b1[col];
#pragma unroll
        for (int r = 0; r < 4; ++r) {
            int row = crow0 + r;
            float v = fmaxf(acc[nb][r] + bias, 0.f);
            ushort bv = f2bf(v);
            lh[row][col] = bv;
            if (m0 + row < N_DST2) hb[(size_t)(m0 + row) * H_F + col] = bv;
        }
    }
    __syncthreads();

    // ---- y = lh @ Wn2, wave w handles k in [w*64, w*64+64) ----
    f32x4 acc2[3];
#pragma unroll
    for (int q = 0; q < 3; ++q) acc2[q] = (f32x4){0.f, 0.f, 0.f, 0.f};
#pragma unroll
    for (int i = 0; i < 2; ++i) {
        int kb = wave * 2 + i;           // local k0 = kb*32
        short8 a = *(const short8*)&lh[mloc][kb * 32 + koff];
#pragma unroll
        for (int q = 0; q < 3; ++q) {
            short8 b = *(const short8*)(P2 + ((size_t)((8 + kb) * 3 + q) * 64 + lane) * 8);
            acc2[q] = __builtin_amdgcn_mfma_f32_16x16x32_bf16(a, b, acc2[q], 0, 0, 0);
        }
    }
    if (wave != 0) {
#pragma unroll
        for (int q = 0; q < 3; ++q) pred[wave - 1][q][lane] = acc2[q];
    }
    __syncthreads();
    if (wave == 0) {
#pragma unroll
        for (int q = 0; q < 3; ++q) {
            f32x4 v = acc2[q];
            v += pred[0][q][lane]; v += pred[1][q][lane]; v += pred[2][q][lane];
#pragma unroll
            for (int r = 0; r < 4; ++r)
                y[(size_t)(m0 + crow0 + r) * 64 + q * 16 + ccol] = f2bf(v[r]);
        }
#pragma unroll
        for (int r = 0; r < 4; ++r)      // zero pad cols 48..63
            y[(size_t)(m0 + crow0 + r) * 64 + 48 + ccol] = 0;
    }
}

// ---- layer-2 mean agg over y rows (128 B bf16): one wave/dst ----
// Same structure as agg1b; accumulates bf16 (shift-unpack) instead of fp8.
__global__ __launch_bounds__(256) void agg2y(const ushort* __restrict__ y,
                                             const int* __restrict__ src,
                                             const int* __restrict__ rp,
                                             float* __restrict__ yagg) {
    int t = threadIdx.x & 63;
    int d = blockIdx.x * 4 + (threadIdx.x >> 6);
    int s = rp[d], e = rp[d + 1];
    int deg = e - s;
    const uint4* y4 = (const uint4*)y;  // row stride 8 uint4 (128 B)
    int g = t >> 3, c = t & 7;
    float a[8] = {};
    auto accv = [&](uint4 v) {
        a[0] += bflo(v.x); a[1] += bfhi(v.x);
        a[2] += bflo(v.y); a[3] += bfhi(v.y);
        a[4] += bflo(v.z); a[5] += bfhi(v.z);
        a[6] += bflo(v.w); a[7] += bfhi(v.w);
    };
    for (int b0 = s; b0 < e; b0 += 64) {
        int nb = min(64, e - b0);
        int idx = 0;
        if (t < nb) idx = src[b0 + t];  // coalesced
        int nfull = nb >> 3;
        int j = 0;
        for (; j + 4 <= nfull; j += 4) {
            int e0 = __shfl(idx, (j + 0) * 8 + g);
            int e1 = __shfl(idx, (j + 1) * 8 + g);
            int e2 = __shfl(idx, (j + 2) * 8 + g);
            int e3 = __shfl(idx, (j + 3) * 8 + g);
            uint4 v0 = y4[(size_t)e0 * 8 + c];
            uint4 v1 = y4[(size_t)e1 * 8 + c];
            uint4 v2 = y4[(size_t)e2 * 8 + c];
            uint4 v3 = y4[(size_t)e3 * 8 + c];
            accv(v0); accv(v1); accv(v2); accv(v3);
        }
        for (; j < nfull; ++j) {
            int e0 = __shfl(idx, j * 8 + g);
            uint4 v = y4[(size_t)e0 * 8 + c];
            accv(v);
        }
        int rem = nb & 7;
        int er = __shfl(idx, (nfull * 8 + g) & 63);  // all lanes active here
        if (g < rem) {
            uint4 v = y4[(size_t)er * 8 + c];
            accv(v);
        }
    }
    // reduce over edge-slots g (lanes xor 8,16,32)
#pragma unroll
    for (int q = 0; q < 8; ++q) {
        float av = a[q];
        av += __shfl_xor(av, 8);
        av += __shfl_xor(av, 16);
        av += __shfl_xor(av, 32);
        a[q] = av;
    }
    if (t < 8) {  // lane c==t owns y cols t*8..t*8+7
        float inv = 1.f / fmaxf((float)deg, 1.f);
        float4 o0 = make_float4(a[0] * inv, a[1] * inv, a[2] * inv, a[3] * inv);
        float4 o1 = make_float4(a[4] * inv, a[5] * inv, a[6] * inv, a[7] * inv);
        float4* row = (float4*)(yagg + (size_t)d * 64 + t * 8);
        row[0] = o0;
        row[1] = o1;
    }
}

// ---- layer 2 GEMM: self path hb@Ws2 (K=256) + precomputed neighbor yagg ----
__global__ __launch_bounds__(256) void gemm2_mfma(
    const ushort* __restrict__ hb, const float* __restrict__ yagg,
    const ushort* __restrict__ P2, const float* __restrict__ b2,
    float* __restrict__ out) {
    int tid = threadIdx.x;
    int wave = tid >> 6, lane = tid & 63;
    int m0 = (blockIdx.x * 4 + wave) * 16;
    if (m0 >= N_DST2) return;
    int mrow = m0 + (lane & 15);
    int koff = (lane >> 4) * 8;

    f32x4 acc[3];
#pragma unroll
    for (int nb = 0; nb < 3; ++nb) acc[nb] = (f32x4){0.f, 0.f, 0.f, 0.f};

#pragma unroll
    for (int kb = 0; kb < 8; ++kb) {
        short8 a = *(const short8*)(hb + (size_t)mrow * H_F + kb * 32 + koff);
#pragma unroll
        for (int nb = 0; nb < 3; ++nb) {
            short8 b = *(const short8*)(P2 + ((size_t)(kb * 3 + nb) * 64 + lane) * 8);
            acc[nb] = __builtin_amdgcn_mfma_f32_16x16x32_bf16(a, b, acc[nb], 0, 0, 0);
        }
    }
    int crow0 = m0 + (lane >> 4) * 4;
    int ccol  = lane & 15;
#pragma unroll
    for (int nb = 0; nb < 3; ++nb) {
        int col = nb * 16 + ccol;
        if (col < N_CLS) {
            float bias = b2[col];
#pragma unroll
            for (int r = 0; r < 4; ++r) {
                float nv = yagg[(size_t)(crow0 + r) * 64 + col];
                out[(size_t)(crow0 + r) * N_CLS + col] = acc[nb][r] + nv + bias;
            }
        }
    }
}

extern "C" void kernel_launch(void* const* d_in, const int* in_sizes, int n_in,
                              void* d_out, int out_size, void* d_ws, size_t ws_size,
                              hipStream_t stream) {
    const float* x   = (const float*)d_in[0];
    const float* Ws1 = (const float*)d_in[1];
    const float* Wn1 = (const float*)d_in[2];
    const float* b1  = (const float*)d_in[3];
    const float* Ws2 = (const float*)d_in[4];
    const float* Wn2 = (const float*)d_in[5];
    const float* b2  = (const float*)d_in[6];
    const int* src1  = (const int*)d_in[7];
    const int* dst1  = (const int*)d_in[8];
    const int* src2  = (const int*)d_in[9];
    const int* dst2  = (const int*)d_in[10];
    float* out = (float*)d_out;

    char* ws = (char*)d_ws;
    int*           rp1 = (int*)(ws + RP1_OFF);
    int*           rp2 = (int*)(ws + RP2_OFF);
    ushort*        bps = (ushort*)(ws + BPS_OFF);
    ushort*        bpn = (ushort*)(ws + BPN_OFF);
    ushort*        bp2 = (ushort*)(ws + BP2_OFF);
    unsigned char* x8  = (unsigned char*)(ws + X8_OFF);
    ushort*        hn1 = (ushort*)(ws + HN1_OFF);
    ushort*        hb  = (ushort*)(ws + HB_OFF);
    ushort*        y   = (ushort*)(ws + Y_OFF);
    float*         yagg= (float*)(ws + YAGG_OFF);

    setup_all<<<CAST_BLKS + PACK_BLKS + RP_BLKS, 256, 0, stream>>>(
        x, x8, Ws1, Wn1, Ws2, Wn2, bps, bpn, bp2, dst1, dst2, rp1, rp2);
    agg1b<<<N_DST1 / 4, 256, 0, stream>>>(x8, src1, rp1, hn1);
    gemm1_mfma<<<N_DST1 / 16, 256, 0, stream>>>(x, hn1, bps, bpn, bp2, b1, hb, y);
    agg2y<<<N_DST2 / 4, 256, 0, stream>>>(y, src2, rp2, yagg);
    gemm2_mfma<<<(N_DST2 / 16 + 3) / 4, 256, 0, stream>>>(hb, yagg, bp2, b2, out);
}